// Round 11
// baseline (495.833 us; speedup 1.0000x reference)
//
#include <hip/hip_runtime.h>

// SingleStageDetector, R20 = R19 + partial-buffer STRIDE FIX.
// R18/R19 failed with bitwise-identical absmax 0.629 (deterministic, NOT a
// race): writer staged partials at (b*4+kq)*HP_IMG (kq-stride = a whole
// image, 26624 u32) while the finisher read kq-stride 128*52 = 6656 u32 ->
// it summed kq=0's partial + 3 reads of zero-filled workspace (h from 320 of
// 1280 channels). Fix: HP_KQ = 128*52 per (image,kq); writer base =
// (b*4+kq)*HP_KQ. R19's release-pattern fix (stores -> fence -> syncthreads
// -> tid0 ticket) retained.
//
// Design (K-split partial GEMM1 + last-block finisher, unmeasured so far):
// R9-R16 all pinned at 42-56us streaming the whole 327KB W1-frag image per
// block at 8-16 waves/CU; per-CU bytes / TLP was the invariant wall.
// Here: block = (kq, image), grid 1024; per block: A-frags 80KB + contiguous
// F-slice 62.7KB; LDS 32KB, launch_bounds(512,6) -> 24 waves/CU; barrier-
// free 10-step K-loop; partial h -> ws; last block per image (atomic ticket,
// counters zeroed by prep_w; no spin) sums 4 partials in fixed order
// (deterministic), bias+leaky -> smHT, then proven GEMM2 + epilogue + IoU.

#define CIN_  1280
#define HW_   49
#define HID_  128
#define OUTD_ 65
#define NGT_  40
#define NP_   441

// flat output offsets (elements), reference return order
#define CONF_OFF 0
#define OFFS_OFF 112896   // 256*9*49
#define CLS_OFF  564480   // + 256*9*4*49
#define IOU_OFF  815360   // + 256*20*49 ; total 5,331,200

// ws layout (u32): W1f frags, W2f frags, partial h, done counters
#define WS_W1F_U32 81920u
#define WS_W2F_U32 5120u
#define HP_OFF     87040u                 // [b][kq][o:128][col:52] f32
#define HP_KQ      (128u*52u)             // 6656 u32 per (image,kq)
#define HP_IMG     (4u*HP_KQ)             // 26624 u32 per image
#define DONE_OFF   (HP_OFF + 256u*HP_IMG) // 256 u32 counters

typedef __bf16 bf16x8 __attribute__((ext_vector_type(8)));
typedef float  f32x4  __attribute__((ext_vector_type(4)));

__device__ __forceinline__ unsigned pack2bf(float lo, float hi) {
    unsigned short a = __builtin_bit_cast(unsigned short, (__bf16)lo);
    unsigned short b = __builtin_bit_cast(unsigned short, (__bf16)hi);
    return (unsigned)a | ((unsigned)b << 16);   // v_cvt_pk_bf16_f32
}
__device__ __forceinline__ float sigmoidf_(float v) { return 1.f / (1.f + __expf(-v)); }

__device__ __forceinline__ bf16x8 ld_frag(const unsigned* p) {
    union { uint4 u; bf16x8 v; } x;
    x.u = *(const uint4*)p;                       // ds_read_b128
    return x.v;
}
__device__ __forceinline__ bf16x8 as_bf(uint4 u) {
    union { uint4 u; bf16x8 v; } x; x.u = u; return x.v;
}

// ---------------------------------------------------------------------------
// prep_w: W1/W2 -> fragment-ready bf16 images (R8) + zero done counters.
// ---------------------------------------------------------------------------
__global__ __launch_bounds__(256) void prep_w(
    const float* __restrict__ W1, const float* __restrict__ W2,
    unsigned* __restrict__ ws)
{
    int X = blockIdx.x * 256 + threadIdx.x;       // 0..87039
    if (X < 256) ws[DONE_OFF + X] = 0u;           // reset finisher counters
    if (X < (int)WS_W1F_U32) {
        int sub = X & 3, lane = (X >> 2) & 63, f = X >> 8;
        int mt = f & 7, K32 = f >> 3;
        int o = mt * 16 + (lane & 15);
        int c = K32 * 32 + (lane >> 4) * 8 + sub * 2;
        float2 v = *(const float2*)(W1 + o * CIN_ + c);
        ws[X] = pack2bf(v.x, v.y);
    } else {
        int Y = X - (int)WS_W1F_U32;              // 0..5119
        int sub = Y & 3, lane = (Y >> 2) & 63, f = Y >> 8;
        int mt2 = f % 5, ks2 = f / 5;
        int o2 = mt2 * 16 + (lane & 15);
        int c = ks2 * 32 + (lane >> 4) * 8 + sub * 2;
        unsigned val = 0;
        if (o2 < OUTD_) {
            float2 v = *(const float2*)(W2 + o2 * HID_ + c);
            val = pack2bf(v.x, v.y);
        }
        ws[WS_W1F_U32 + Y] = val;
    }
}

// ---------------------------------------------------------------------------
// fused_main: block id = kq*256 + b (4 kq-blocks of an image -> same XCD).
// LDS: F-slice as bf16 ch-pairs, [col:49][cp:160 pad 164] u32 = 32,144 B.
// Finisher aliases it as smHT[64][68].
// ---------------------------------------------------------------------------
__global__ __launch_bounds__(512, 6) void fused_main(
    const float* __restrict__ F,     // (256,1280,7,7)
    const float* __restrict__ grd,   // (256,7,7,2)
    const float* __restrict__ bbox,  // (256,40,5)
    const float* __restrict__ anc,   // (9,2)
    const unsigned* __restrict__ wsW,
    float* __restrict__ wsF,         // same buffer, for partials/counters
    const float* __restrict__ B1,    // (128,)
    const float* __restrict__ B2,    // (65,)
    float* __restrict__ out)
{
    __shared__ __align__(16) unsigned lds[49 * 164];   // 32,144 B
    __shared__ int isLast;

    const int tid  = threadIdx.x;
    const int id   = blockIdx.x;
    const int kq   = id >> 8;          // 0..3 K-quarter
    const int b    = id & 255;         // image
    const int lane = tid & 63;
    const int w    = tid >> 6;         // 0..7 = m-tile
    const int quad = lane >> 4;
    const int m16  = lane & 15;

    // ---- stage F-slice (320ch x 49col, contiguous 62.7KB) as bf16 pairs ----
    // item i -> cp = i/49 (ch-pair), col = i%49; lds[col*164 + cp].
    const float* Fsl = F + b * (CIN_ * HW_) + kq * 15680;
    #pragma unroll
    for (int it = 0; it < 16; ++it) {
        int i = it * 512 + tid;
        if (i < 7840) {
            int cp = i / 49, col = i - cp * 49;
            float v0 = Fsl[cp * 98 + col];
            float v1 = Fsl[cp * 98 + 49 + col];
            lds[col * 164 + cp] = pack2bf(v0, v1);
        }
    }
    __syncthreads();   // the only GEMM1 barrier

    // ---- K-loop: 10 K32-steps, barrier-free, 2-deep A prefetch ----
    // wave w = m-tile w; 4 n-tiles (49 cols padded, col clamped to 48).
    const uint4* AFs = (const uint4*)wsW + (kq * 80 + w) * 64 + lane; // +k*8*64
    int colc[4];
    #pragma unroll
    for (int nt = 0; nt < 4; ++nt) {
        int c = nt * 16 + m16;
        colc[nt] = (c < HW_ ? c : HW_ - 1) * 164 + quad * 4;
    }
    f32x4 acc[4] = {(f32x4)(0.f), (f32x4)(0.f), (f32x4)(0.f), (f32x4)(0.f)};
    uint4 a0 = AFs[0], a1 = AFs[512];
    #pragma unroll
    for (int k = 0; k < 10; ++k) {
        uint4 an = AFs[(k < 8 ? k + 2 : 9) * 512];
        bf16x8 A = as_bf(a0);
        #pragma unroll
        for (int nt = 0; nt < 4; ++nt) {
            bf16x8 Bf = ld_frag(lds + colc[nt] + k * 16);
            acc[nt] = __builtin_amdgcn_mfma_f32_16x16x32_bf16(A, Bf, acc[nt], 0, 0, 0);
        }
        a0 = a1; a1 = an;
    }

    // ---- store partial h: hp[b][kq][o][col], kq-stride = HP_KQ (the fix) ----
    {
        float* hp = wsF + HP_OFF + (unsigned)(b * 4 + kq) * HP_KQ;
        #pragma unroll
        for (int nt = 0; nt < 4; ++nt) {
            int col = nt * 16 + m16;
            if (col < HW_) {
                #pragma unroll
                for (int r = 0; r < 4; ++r) {
                    int o = w * 16 + quad * 4 + r;
                    hp[o * 52 + col] = acc[nt][r];
                }
            }
        }
    }

    // ---- last-block-per-image finisher handoff (no spin, no deadlock) ----
    __threadfence();   // each thread: release its own partial stores
    __syncthreads();   // all threads stored+fenced before the ticket
    if (tid == 0) {
        unsigned old = atomicAdd((unsigned*)wsF + DONE_OFF + b, 1u);
        isLast = (old == 3u);
    }
    __syncthreads();
    if (!isLast) return;
    __threadfence();                               // acquire others' partials

    // ---- finisher: sum 4 partials -> bias+leaky -> smHT[col][op] bf16 ----
    unsigned* smHT = lds;                          // alias (K-loop done)
    for (int i = tid; i < 15 * 68; i += 512)       // zero pad rows 49..63
        smHT[(49 + i / 68) * 68 + (i % 68)] = 0u;
    const float* hpb = wsF + HP_OFF + (unsigned)b * HP_IMG;
    #pragma unroll
    for (int it = 0; it < 7; ++it) {
        int i = it * 512 + tid;                    // (op, col), 64*49 items
        if (i < 3136) {
            int op = i / 49, col = i - op * 49;
            int o0 = 2 * op;
            float s0 = 0.f, s1 = 0.f;
            #pragma unroll
            for (int q2 = 0; q2 < 4; ++q2) {
                s0 += hpb[q2 * HP_KQ + (o0    ) * 52 + col];
                s1 += hpb[q2 * HP_KQ + (o0 + 1) * 52 + col];
            }
            s0 += B1[o0]; s1 += B1[o0 + 1];
            s0 = s0 > 0.f ? s0 : 0.01f * s0;
            s1 = s1 > 0.f ? s1 : 0.01f * s1;
            smHT[col * 68 + op] = pack2bf(s0, s1);
        }
    }
    __syncthreads();   // smHT ready

    // ---- GEMM2: 20 tiles (5 o2 x 4 hw); wave w: T = w, w+8, w+16 ----
    for (int T = w; T < 20; T += 8) {
        int m2 = T % 5, nt2 = T / 5;
        const uint4* A2p = (const uint4*)(wsW + WS_W1F_U32) + m2 * 64 + lane;
        uint4 a20 = A2p[0], a21 = A2p[320], a22 = A2p[640], a23 = A2p[960];
        f32x4 c2 = (f32x4)(0.f);
        const unsigned* Bb = smHT + (nt2 * 16 + m16) * 68 + quad * 4;
        c2 = __builtin_amdgcn_mfma_f32_16x16x32_bf16(as_bf(a20), ld_frag(Bb +  0), c2, 0, 0, 0);
        c2 = __builtin_amdgcn_mfma_f32_16x16x32_bf16(as_bf(a21), ld_frag(Bb + 16), c2, 0, 0, 0);
        c2 = __builtin_amdgcn_mfma_f32_16x16x32_bf16(as_bf(a22), ld_frag(Bb + 32), c2, 0, 0, 0);
        c2 = __builtin_amdgcn_mfma_f32_16x16x32_bf16(as_bf(a23), ld_frag(Bb + 48), c2, 0, 0, 0);
        int hw = nt2 * 16 + m16;
        if (hw < HW_) {
            #pragma unroll
            for (int r = 0; r < 4; ++r) {
                int o2 = m2 * 16 + quad * 4 + r;
                if (o2 >= OUTD_) continue;
                float aa = c2[r] + B2[o2];
                unsigned dst; float val;
                if (o2 < 36) {
                    int an9 = o2 >> 2, kk = o2 & 3;
                    val = (kk < 2) ? (sigmoidf_(aa) - 0.5f) : aa;
                    dst = OFFS_OFF + b * 1764 + an9 * 196 + kk * 49 + hw;
                } else if (o2 < 45) {
                    val = sigmoidf_(aa);
                    dst = CONF_OFF + b * 441 + (o2 - 36) * 49 + hw;
                } else {
                    val = aa;
                    dst = CLS_OFF + b * 980 + (o2 - 45) * 49 + hw;
                }
                out[dst] = val;
            }
        }
    }

    // ---- IoU: wave-uniform p, g = lane (<40), coalesced stores ----
    {
        int gl = (lane < NGT_) ? lane : 0;
        const float* gb = bbox + b * 200 + gl * 5;
        float gx1 = gb[0], gy1 = gb[1], gx2 = gb[2], gy2 = gb[3];
        float gA = (gx2 - gx1) * (gy2 - gy1);
        #pragma unroll 4
        for (int p = w; p < NP_; p += 8) {
            int a9 = p / 49, r = p - a9 * 49;
            float2 ct = *(const float2*)(grd + b * 98 + 2 * r);
            float hx = anc[2 * a9] * 0.5f,  hy = anc[2 * a9 + 1] * 0.5f;
            float px1 = ct.x - hx, py1 = ct.y - hy, px2 = ct.x + hx, py2 = ct.y + hy;
            float pA = (px2 - px1) * (py2 - py1);
            float legal = (fminf(fminf(px1, py1), fminf(px2, py2)) > 0.f) ? 1.f : 0.f;
            float tlx = fmaxf(px1, gx1), tly = fmaxf(py1, gy1);
            float brx = fminf(px2, gx2), bry = fminf(py2, gy2);
            float dx = fmaxf(brx - tlx, 0.f), dy = fmaxf(bry - tly, 0.f);
            float inter = dx * dy * legal;
            float iou = __fdividef(inter, gA + pA - inter);
            if (lane < NGT_)
                out[IOU_OFF + b * (NP_ * NGT_) + p * 40 + lane] = iou;
        }
    }
}

extern "C" void kernel_launch(void* const* d_in, const int* in_sizes, int n_in,
                              void* d_out, int out_size, void* d_ws, size_t ws_size,
                              hipStream_t stream) {
    const float* F  = (const float*)d_in[0];
    const float* G  = (const float*)d_in[1];
    const float* BB = (const float*)d_in[2];
    const float* AN = (const float*)d_in[3];
    const float* W1 = (const float*)d_in[4];
    const float* B1 = (const float*)d_in[5];
    const float* W2 = (const float*)d_in[6];
    const float* B2 = (const float*)d_in[7];
    float* out = (float*)d_out;
    unsigned* wsu = (unsigned*)d_ws;

    prep_w<<<340, 256, 0, stream>>>(W1, W2, wsu);
    fused_main<<<1024, 512, 0, stream>>>(F, G, BB, AN, wsu, (float*)d_ws,
                                         B1, B2, out);
}

// Round 12
// 141.862 us; speedup vs baseline: 3.4952x; 3.4952x over previous
//
#include <hip/hip_runtime.h>

// SingleStageDetector, R21 = fragment-ready F pre-pass + streaming GEMM1.
// R20 post-mortem: cross-block finisher worked but device-scope fences
// (required by non-coherent per-XCD L2s) invalidate L2 ~256x/XCD -> all
// loads cold, 420us. Cross-block reduction abandoned.
// Session invariant (R9-R16, 42-56us): B-frags need 8 ch-strided values per
// lane -> either LDS staging (barrier-phased, vmem pipe drained per chunk)
// or 16 scalar loads (issue/latency-bound). R21 fixes the LAYOUT: prep pass
// writes F as fragment-ready bf16 images (same proven transform prep_w does
// for W1). GEMM1 becomes a pure register stream: 5 dwordx4 loads + 4 MFMA
// per K-step, zero LDS, zero barriers, 3-deep rolling prefetch (rolling
// uint4 MFMA operands survived the compiler in R13; only LDS-staging regs
// collapsed). Block = image, 16 waves (1024 thr) for latency cover; wave =
// (o-tile wo, ct-half), acc[2]. Proven tail (h -> smHT -> GEMM2 -> IoU)
// in-block, no atomics/fences. prep: merged grid (F-frags + W-frags).

#define CIN_  1280
#define HW_   49
#define HID_  128
#define OUTD_ 65
#define NGT_  40
#define NP_   441

// flat output offsets (elements), reference return order
#define CONF_OFF 0
#define OFFS_OFF 112896   // 256*9*49
#define CLS_OFF  564480   // + 256*9*4*49
#define IOU_OFF  815360   // + 256*20*49 ; total 5,331,200

// ws layout (u32): W1f frags, W2f frags, F frags
#define WS_W1F_U32 81920u
#define WS_W2F_U32 5120u
#define FB_OFF     87040u                  // F-frag: 256*40*4*64 uint4 = 42MB

typedef __bf16 bf16x8 __attribute__((ext_vector_type(8)));
typedef float  f32x4  __attribute__((ext_vector_type(4)));

__device__ __forceinline__ unsigned pack2bf(float lo, float hi) {
    unsigned short a = __builtin_bit_cast(unsigned short, (__bf16)lo);
    unsigned short b = __builtin_bit_cast(unsigned short, (__bf16)hi);
    return (unsigned)a | ((unsigned)b << 16);   // v_cvt_pk_bf16_f32
}
__device__ __forceinline__ float sigmoidf_(float v) { return 1.f / (1.f + __expf(-v)); }

__device__ __forceinline__ bf16x8 ld_frag(const unsigned* p) {
    union { uint4 u; bf16x8 v; } x;
    x.u = *(const uint4*)p;                       // ds_read_b128
    return x.v;
}
__device__ __forceinline__ bf16x8 as_bf(uint4 u) {
    union { uint4 u; bf16x8 v; } x; x.u = u; return x.v;
}

// ---------------------------------------------------------------------------
// prep: blocks [0,10240) -> F-frags; [10240,10580) -> W1/W2 frags (R8 code).
// F-frag thread X (one uint4): X = ((b*40+k32)*4+ct)*64 + lane.
//   u32 s of lane = pack(F[ch][col], F[ch+1][col]), ch = k32*32+quad*8+2s,
//   col = min(ct*16+m16, 48)  (clamped pad cols -> finite dupes, masked later)
// ---------------------------------------------------------------------------
__global__ __launch_bounds__(256) void prep(
    const float* __restrict__ F,
    const float* __restrict__ W1, const float* __restrict__ W2,
    unsigned* __restrict__ ws)
{
    if (blockIdx.x < 10240) {
        int X = blockIdx.x * 256 + threadIdx.x;   // uint4 index
        int lane = X & 63, t = X >> 6;
        int ct = t & 3, bk = t >> 2;
        int k32 = bk % 40, b = bk / 40;
        int quad = lane >> 4, m16 = lane & 15;
        int col = ct * 16 + m16; if (col > 48) col = 48;
        const float* p = F + b * (CIN_ * HW_) + (k32 * 32 + quad * 8) * 49 + col;
        uint4 q;
        q.x = pack2bf(p[0],   p[49]);
        q.y = pack2bf(p[98],  p[147]);
        q.z = pack2bf(p[196], p[245]);
        q.w = pack2bf(p[294], p[343]);
        ((uint4*)(ws + FB_OFF))[X] = q;
        return;
    }
    int X = (blockIdx.x - 10240) * 256 + threadIdx.x;   // 0..87039
    if (X < (int)WS_W1F_U32) {
        int sub = X & 3, lane = (X >> 2) & 63, f = X >> 8;
        int mt = f & 7, K32 = f >> 3;
        int o = mt * 16 + (lane & 15);
        int c = K32 * 32 + (lane >> 4) * 8 + sub * 2;
        float2 v = *(const float2*)(W1 + o * CIN_ + c);
        ws[X] = pack2bf(v.x, v.y);
    } else {
        int Y = X - (int)WS_W1F_U32;              // 0..5119
        int sub = Y & 3, lane = (Y >> 2) & 63, f = Y >> 8;
        int mt2 = f % 5, ks2 = f / 5;
        int o2 = mt2 * 16 + (lane & 15);
        int c = ks2 * 32 + (lane >> 4) * 8 + sub * 2;
        unsigned val = 0;
        if (o2 < OUTD_) {
            float2 v = *(const float2*)(W2 + o2 * HID_ + c);
            val = pack2bf(v.x, v.y);
        }
        ws[WS_W1F_U32 + Y] = val;
    }
}

// ---------------------------------------------------------------------------
// fused_main: 1 block per image, 1024 thr = 16 waves. Wave w: o-tile
// wo = w>>1 (16 outputs), ct-half ch2 = w&1 (cols ch2*32..+31 as 2 ct tiles).
// GEMM1: 40-step barrier-free stream, 3-deep rolling prefetch, 3 uint4
// loads + 2 MFMA per step. LDS: smHT[64][68] only (17,408 B).
// ---------------------------------------------------------------------------
__global__ __launch_bounds__(1024, 4) void fused_main(
    const float* __restrict__ grd,   // (256,7,7,2)
    const float* __restrict__ bbox,  // (256,40,5)
    const float* __restrict__ anc,   // (9,2)
    const unsigned* __restrict__ wsW,
    const float* __restrict__ B1,    // (128,)
    const float* __restrict__ B2,    // (65,)
    float* __restrict__ out)
{
    __shared__ __align__(16) unsigned smHT[64 * 68];   // 17,408 B

    const int tid  = threadIdx.x;
    const int b    = blockIdx.x;
    const int lane = tid & 63;
    const int w    = tid >> 6;         // 0..15
    const int wo   = w >> 1;           // o-tile 0..7
    const int ch2  = w & 1;            // ct-half
    const int quad = lane >> 4;
    const int m16  = lane & 15;

    // A-frags: (k*8 + wo)*64 + lane ; B-frags: b*10240 + k*256 + ct*64 + lane
    const uint4* Ap = (const uint4*)wsW + wo * 64 + lane;            // +k*512
    const uint4* Fp = (const uint4*)(wsW + FB_OFF) + b * 10240 + ch2 * 128 + lane;
    #define LD_A(k)    Ap[(k) * 512]
    #define LD_B(k, j) Fp[(k) * 256 + (j) * 64]

    f32x4 acc[2] = {(f32x4)(0.f), (f32x4)(0.f)};
    uint4 ar[3], br[3][2];
    #pragma unroll
    for (int d = 0; d < 3; ++d) {
        ar[d] = LD_A(d);
        br[d][0] = LD_B(d, 0);
        br[d][1] = LD_B(d, 1);
    }
    #pragma unroll
    for (int k = 0; k < 40; ++k) {               // full unroll: k%3 static
        const int s = k % 3;
        bf16x8 A = as_bf(ar[s]);
        acc[0] = __builtin_amdgcn_mfma_f32_16x16x32_bf16(A, as_bf(br[s][0]), acc[0], 0, 0, 0);
        acc[1] = __builtin_amdgcn_mfma_f32_16x16x32_bf16(A, as_bf(br[s][1]), acc[1], 0, 0, 0);
        const int kp = (k + 3 < 40) ? k + 3 : 39;
        ar[s] = LD_A(kp);
        br[s][0] = LD_B(kp, 0);
        br[s][1] = LD_B(kp, 1);
    }

    // ---- h: bias + leaky -> smHT[col*68 + o/2] (bf16 pairs) ----
    #pragma unroll
    for (int j = 0; j < 2; ++j) {
        int col = (ch2 * 2 + j) * 16 + m16;
        #pragma unroll
        for (int rp = 0; rp < 2; ++rp) {
            int o0 = wo * 16 + quad * 4 + 2 * rp;
            float v0 = acc[j][2 * rp]     + B1[o0];
            float v1 = acc[j][2 * rp + 1] + B1[o0 + 1];
            v0 = v0 > 0.f ? v0 : 0.01f * v0;
            v1 = v1 > 0.f ? v1 : 0.01f * v1;
            smHT[col * 68 + (o0 >> 1)] = pack2bf(v0, v1);
        }
    }
    __syncthreads();   // smHT ready (rows 49..63 = finite col-48 dupes)

    // ---- GEMM2: 20 tiles (5 o2 x 4 hw); wave w: T = w, w+16 ----
    for (int T = w; T < 20; T += 16) {
        int m2 = T % 5, nt2 = T / 5;
        const uint4* A2p = (const uint4*)(wsW + WS_W1F_U32) + m2 * 64 + lane;
        uint4 a20 = A2p[0], a21 = A2p[320], a22 = A2p[640], a23 = A2p[960];
        f32x4 c2 = (f32x4)(0.f);
        const unsigned* Bb = smHT + (nt2 * 16 + m16) * 68 + quad * 4;
        c2 = __builtin_amdgcn_mfma_f32_16x16x32_bf16(as_bf(a20), ld_frag(Bb +  0), c2, 0, 0, 0);
        c2 = __builtin_amdgcn_mfma_f32_16x16x32_bf16(as_bf(a21), ld_frag(Bb + 16), c2, 0, 0, 0);
        c2 = __builtin_amdgcn_mfma_f32_16x16x32_bf16(as_bf(a22), ld_frag(Bb + 32), c2, 0, 0, 0);
        c2 = __builtin_amdgcn_mfma_f32_16x16x32_bf16(as_bf(a23), ld_frag(Bb + 48), c2, 0, 0, 0);
        int hw = nt2 * 16 + m16;
        if (hw < HW_) {
            #pragma unroll
            for (int r = 0; r < 4; ++r) {
                int o2 = m2 * 16 + quad * 4 + r;
                if (o2 >= OUTD_) continue;
                float aa = c2[r] + B2[o2];
                unsigned dst; float val;
                if (o2 < 36) {
                    int an9 = o2 >> 2, kk = o2 & 3;
                    val = (kk < 2) ? (sigmoidf_(aa) - 0.5f) : aa;
                    dst = OFFS_OFF + b * 1764 + an9 * 196 + kk * 49 + hw;
                } else if (o2 < 45) {
                    val = sigmoidf_(aa);
                    dst = CONF_OFF + b * 441 + (o2 - 36) * 49 + hw;
                } else {
                    val = aa;
                    dst = CLS_OFF + b * 980 + (o2 - 45) * 49 + hw;
                }
                out[dst] = val;
            }
        }
    }

    // ---- IoU: wave-uniform p, g = lane (<40), coalesced stores ----
    {
        int gl = (lane < NGT_) ? lane : 0;
        const float* gb = bbox + b * 200 + gl * 5;
        float gx1 = gb[0], gy1 = gb[1], gx2 = gb[2], gy2 = gb[3];
        float gA = (gx2 - gx1) * (gy2 - gy1);
        #pragma unroll 4
        for (int p = w; p < NP_; p += 16) {
            int a9 = p / 49, r = p - a9 * 49;
            float2 ct = *(const float2*)(grd + b * 98 + 2 * r);
            float hx = anc[2 * a9] * 0.5f,  hy = anc[2 * a9 + 1] * 0.5f;
            float px1 = ct.x - hx, py1 = ct.y - hy, px2 = ct.x + hx, py2 = ct.y + hy;
            float pA = (px2 - px1) * (py2 - py1);
            float legal = (fminf(fminf(px1, py1), fminf(px2, py2)) > 0.f) ? 1.f : 0.f;
            float tlx = fmaxf(px1, gx1), tly = fmaxf(py1, gy1);
            float brx = fminf(px2, gx2), bry = fminf(py2, gy2);
            float dx = fmaxf(brx - tlx, 0.f), dy = fmaxf(bry - tly, 0.f);
            float inter = dx * dy * legal;
            float iou = __fdividef(inter, gA + pA - inter);
            if (lane < NGT_)
                out[IOU_OFF + b * (NP_ * NGT_) + p * 40 + lane] = iou;
        }
    }
}

extern "C" void kernel_launch(void* const* d_in, const int* in_sizes, int n_in,
                              void* d_out, int out_size, void* d_ws, size_t ws_size,
                              hipStream_t stream) {
    const float* F  = (const float*)d_in[0];
    const float* G  = (const float*)d_in[1];
    const float* BB = (const float*)d_in[2];
    const float* AN = (const float*)d_in[3];
    const float* W1 = (const float*)d_in[4];
    const float* B1 = (const float*)d_in[5];
    const float* W2 = (const float*)d_in[6];
    const float* B2 = (const float*)d_in[7];
    float* out = (float*)d_out;
    unsigned* wsu = (unsigned*)d_ws;

    prep<<<10580, 256, 0, stream>>>(F, W1, W2, wsu);
    fused_main<<<256, 1024, 0, stream>>>(G, BB, AN, wsu, B1, B2, out);
}